// Round 8
// baseline (244.948 us; speedup 1.0000x reference)
//
#include <hip/hip_runtime.h>

typedef _Float16 half8  __attribute__((ext_vector_type(8)));
typedef _Float16 half4v __attribute__((ext_vector_type(4)));
typedef _Float16 half2v __attribute__((ext_vector_type(2)));
typedef float    floatx4 __attribute__((ext_vector_type(4)));
typedef float    float2v __attribute__((ext_vector_type(2)));

static constexpr float INVPI = 0.3183098861837907f;  // weights pre-scaled by 1/pi: MFMA emits z2 = 2*rev
static constexpr float RLOG  = 3.82843f;

// p = x0(1-x0) = 0.125*(1 + cos(2*pi*v)), v = fract(z2) - 0.5 in [-0.5, 0.5).
// Degree-7 Taylor in y = v^2 (error < 5e-6 absolute at the interval edge).
static constexpr float D0 = 0.25f;
static constexpr float D1 = -2.4674011002723395f;
static constexpr float D2 = 8.117424252833536f;
static constexpr float D3 = -10.68210215083671f;
static constexpr float D4 = 7.5305798401416f;
static constexpr float D5 = -3.3032806329063f;
static constexpr float D6 = 0.987941625012f;
static constexpr float D7 = -0.2142998706f;

// out = R^2 * p * (1 - R*p)  (two logistic iterations fused)
__device__ __forceinline__ float act_poly(float z2) {
    float t = __builtin_amdgcn_fractf(z2);
    float v = t - 0.5f;
    float y = v * v;
    float p = __builtin_fmaf(D7, y, D6);
    p = __builtin_fmaf(p, y, D5);
    p = __builtin_fmaf(p, y, D4);
    p = __builtin_fmaf(p, y, D3);
    p = __builtin_fmaf(p, y, D2);
    p = __builtin_fmaf(p, y, D1);
    p = __builtin_fmaf(p, y, D0);
    float w = __builtin_fmaf(p, -RLOG, 1.0f);
    return (RLOG * RLOG * p) * w;
}

__device__ __forceinline__ float2v act2v(float2v z2) {
    float2v t = { __builtin_amdgcn_fractf(z2.x), __builtin_amdgcn_fractf(z2.y) };
    float2v v = t - (float2v)(0.5f);
    float2v y = v * v;
    float2v p = __builtin_elementwise_fma((float2v)(D7), y, (float2v)(D6));
    p = __builtin_elementwise_fma(p, y, (float2v)(D5));
    p = __builtin_elementwise_fma(p, y, (float2v)(D4));
    p = __builtin_elementwise_fma(p, y, (float2v)(D3));
    p = __builtin_elementwise_fma(p, y, (float2v)(D2));
    p = __builtin_elementwise_fma(p, y, (float2v)(D1));
    p = __builtin_elementwise_fma(p, y, (float2v)(D0));
    float2v w = __builtin_elementwise_fma(p, (float2v)(-RLOG), (float2v)(1.0f));
    return (p * (RLOG * RLOG)) * w;
}

// Two C-frags (tiles t, t+2) -> next-layer B-frag directly (no cat shuffles).
__device__ __forceinline__ half8 act8p(floatx4 a, floatx4 b) {
    float2v h0 = act2v(float2v{a[0], a[1]});
    float2v h1 = act2v(float2v{a[2], a[3]});
    float2v h2 = act2v(float2v{b[0], b[1]});
    float2v h3 = act2v(float2v{b[2], b[3]});
    half2v e0 = __builtin_bit_cast(half2v, __builtin_amdgcn_cvt_pkrtz(h0.x, h0.y));
    half2v e1 = __builtin_bit_cast(half2v, __builtin_amdgcn_cvt_pkrtz(h1.x, h1.y));
    half2v e2 = __builtin_bit_cast(half2v, __builtin_amdgcn_cvt_pkrtz(h2.x, h2.y));
    half2v e3 = __builtin_bit_cast(half2v, __builtin_amdgcn_cvt_pkrtz(h3.x, h3.y));
    half4v lo = __builtin_shufflevector(e0, e1, 0, 1, 2, 3);
    half4v hi = __builtin_shufflevector(e2, e3, 0, 1, 2, 3);
    return __builtin_shufflevector(lo, hi, 0, 1, 2, 3, 4, 5, 6, 7);
}

// Register-resident MLP chain on native 16x16x32 f16 MFMA; activation is a
// transcendental-free range-reduced polynomial (v_cos was the bottleneck:
// ~32 issue-cycles each, 48/tile = ~1500 cyc/tile; poly cuts that ~2.5x).
// Next layer's weight COLUMNS are permuted by
//   sigma: k-slot (c, q, j) -> neuron (j<4 ? 16c+4q+j : 16(c+2)+4q+j-4)
// so act8p(acc_t, acc_{t+2}) IS the next B-frag: zero-cost layer transitions.
// 2-way tile jam for in-wave ILP. launch_bounds(256,2): the no-spill config
// ((256,3) spilled in R4 AND R7 -- do not retry without shrinking weights).
__global__ __launch_bounds__(256, 2) void mlp_fused(
    const float* __restrict__ x,
    const float* __restrict__ W1, const float* __restrict__ b1,
    const float* __restrict__ W2, const float* __restrict__ b2,
    const float* __restrict__ W3, const float* __restrict__ b3,
    const float* __restrict__ W4, const float* __restrict__ b4,
    float* __restrict__ out, int N)
{
    const int lane = threadIdx.x & 63;
    const int m    = lane & 15;   // sample / C col / A row
    const int q    = lane >> 4;   // quad
    const float s  = INVPI;
    const floatx4 zero4 = {0.0f, 0.0f, 0.0f, 0.0f};

    // ---------------- per-wave weight prep (reused across all tiles) --------------
    // L1 A-frag (tile t): lanes q==0 hold, for out-neuron n=16t+m, k-slots
    //   [w0h, w0h, w0l, w1h, w1h, w1l, b1h, b1l]   (pairs with xa below)
    half8 w1f[4];
    #pragma unroll
    for (int t = 0; t < 4; ++t) {
        half8 v = {};
        if (q == 0) {
            const int n = 16 * t + m;
            float w0 = W1[2*n] * s, w1 = W1[2*n+1] * s, bb = b1[n] * s;
            _Float16 w0h = (_Float16)w0; float w0l = w0 - (float)w0h;
            _Float16 w1h = (_Float16)w1; float w1l = w1 - (float)w1h;
            _Float16 bh  = (_Float16)bb; float bl  = bb - (float)bh;
            v[0] = w0h; v[1] = w0h; v[2] = (_Float16)w0l;
            v[3] = w1h; v[4] = w1h; v[5] = (_Float16)w1l;
            v[6] = bh;  v[7] = (_Float16)bl;
        }
        w1f[t] = v;
    }

    // L2/L3 A-frags with sigma-permuted columns: two contiguous float4 loads.
    half8 w2f[4][2], w3f[4][2];
    floatx4 bb2[4], bb3[4];
    #pragma unroll
    for (int t = 0; t < 4; ++t) {
        const float* r2 = W2 + (16 * t + m) * 64;
        const float* r3 = W3 + (16 * t + m) * 64;
        #pragma unroll
        for (int c = 0; c < 2; ++c) {
            floatx4 lo2 = *(const floatx4*)(r2 + 16 * c + 4 * q);
            floatx4 hi2 = *(const floatx4*)(r2 + 16 * (c + 2) + 4 * q);
            floatx4 lo3 = *(const floatx4*)(r3 + 16 * c + 4 * q);
            floatx4 hi3 = *(const floatx4*)(r3 + 16 * (c + 2) + 4 * q);
            half8 v2, v3;
            #pragma unroll
            for (int j = 0; j < 4; ++j) {
                v2[j]     = (_Float16)(lo2[j] * s);
                v2[4 + j] = (_Float16)(hi2[j] * s);
                v3[j]     = (_Float16)(lo3[j] * s);
                v3[4 + j] = (_Float16)(hi3[j] * s);
            }
            w2f[t][c] = v2;
            w3f[t][c] = v3;
        }
        bb2[t] = *(const floatx4*)(b2 + 16 * t + 4 * q) * s;   // f32 C-init biases
        bb3[t] = *(const floatx4*)(b3 + 16 * t + 4 * q) * s;
    }

    // L4 A-frag: only out-row m==0 real, same sigma column permutation.
    half8 w4f[2] = {half8{}, half8{}};
    if (m == 0) {
        #pragma unroll
        for (int c = 0; c < 2; ++c) {
            #pragma unroll
            for (int j = 0; j < 8; ++j) {
                int nu = (j < 4) ? (16 * c + 4 * q + j) : (16 * (c + 2) + 4 * q + j - 4);
                w4f[c][j] = (_Float16)(W4[nu] * s);
            }
        }
    }
    floatx4 a4init = zero4;
    if (q == 0) a4init[0] = b4[0] * s;       // C row 0 = (q=0, r=0)

    const int npairs = N >> 5;               // pairs of 16-row tiles
    const int nwaves = (gridDim.x * blockDim.x) >> 6;
    const int gwave  = (int)(blockIdx.x * blockDim.x + threadIdx.x) >> 6;
    const float2* __restrict__ x2 = (const float2*)x;

    int pair = gwave;
    float2 xv[2] = { x2[(pair << 5) + m], x2[(pair << 5) + 16 + m] };  // prefetched
    while (pair < npairs) {
        const int np = pair + nwaves;
        float2 xn[2];
        if (np < npairs) {
            xn[0] = x2[(np << 5) + m];
            xn[1] = x2[(np << 5) + 16 + m];
        }

        // L1 B-frags (lanes q==0): [xh, xl, xh, yh, yl, yh, 1, 1]
        half8 xa[2] = {half8{}, half8{}};
        #pragma unroll
        for (int u = 0; u < 2; ++u) {
            if (q == 0) {
                _Float16 xh = (_Float16)xv[u].x; float xl = xv[u].x - (float)xh;
                _Float16 yh = (_Float16)xv[u].y; float yl = xv[u].y - (float)yh;
                xa[u][0] = xh; xa[u][1] = (_Float16)xl; xa[u][2] = xh;
                xa[u][3] = yh; xa[u][4] = (_Float16)yl; xa[u][5] = yh;
                xa[u][6] = (_Float16)1.0f; xa[u][7] = (_Float16)1.0f;
            }
        }

        // ---- layer 1 (two independent chains interleaved) ----
        half8 B0[2], B1[2];
        #pragma unroll
        for (int u = 0; u < 2; ++u) {
            floatx4 a0 = __builtin_amdgcn_mfma_f32_16x16x32_f16(w1f[0], xa[u], zero4, 0, 0, 0);
            floatx4 a1 = __builtin_amdgcn_mfma_f32_16x16x32_f16(w1f[1], xa[u], zero4, 0, 0, 0);
            floatx4 a2 = __builtin_amdgcn_mfma_f32_16x16x32_f16(w1f[2], xa[u], zero4, 0, 0, 0);
            floatx4 a3 = __builtin_amdgcn_mfma_f32_16x16x32_f16(w1f[3], xa[u], zero4, 0, 0, 0);
            B0[u] = act8p(a0, a2);
            B1[u] = act8p(a1, a3);
        }

        // ---- layer 2 ----
        half8 C0[2], C1[2];
        #pragma unroll
        for (int u = 0; u < 2; ++u) {
            floatx4 a0 = __builtin_amdgcn_mfma_f32_16x16x32_f16(w2f[0][0], B0[u], bb2[0], 0, 0, 0);
            floatx4 a1 = __builtin_amdgcn_mfma_f32_16x16x32_f16(w2f[1][0], B0[u], bb2[1], 0, 0, 0);
            floatx4 a2 = __builtin_amdgcn_mfma_f32_16x16x32_f16(w2f[2][0], B0[u], bb2[2], 0, 0, 0);
            floatx4 a3 = __builtin_amdgcn_mfma_f32_16x16x32_f16(w2f[3][0], B0[u], bb2[3], 0, 0, 0);
            a0 = __builtin_amdgcn_mfma_f32_16x16x32_f16(w2f[0][1], B1[u], a0, 0, 0, 0);
            a1 = __builtin_amdgcn_mfma_f32_16x16x32_f16(w2f[1][1], B1[u], a1, 0, 0, 0);
            a2 = __builtin_amdgcn_mfma_f32_16x16x32_f16(w2f[2][1], B1[u], a2, 0, 0, 0);
            a3 = __builtin_amdgcn_mfma_f32_16x16x32_f16(w2f[3][1], B1[u], a3, 0, 0, 0);
            C0[u] = act8p(a0, a2);
            C1[u] = act8p(a1, a3);
        }

        // ---- layer 3 ----
        half8 E0[2], E1[2];
        #pragma unroll
        for (int u = 0; u < 2; ++u) {
            floatx4 a0 = __builtin_amdgcn_mfma_f32_16x16x32_f16(w3f[0][0], C0[u], bb3[0], 0, 0, 0);
            floatx4 a1 = __builtin_amdgcn_mfma_f32_16x16x32_f16(w3f[1][0], C0[u], bb3[1], 0, 0, 0);
            floatx4 a2 = __builtin_amdgcn_mfma_f32_16x16x32_f16(w3f[2][0], C0[u], bb3[2], 0, 0, 0);
            floatx4 a3 = __builtin_amdgcn_mfma_f32_16x16x32_f16(w3f[3][0], C0[u], bb3[3], 0, 0, 0);
            a0 = __builtin_amdgcn_mfma_f32_16x16x32_f16(w3f[0][1], C1[u], a0, 0, 0, 0);
            a1 = __builtin_amdgcn_mfma_f32_16x16x32_f16(w3f[1][1], C1[u], a1, 0, 0, 0);
            a2 = __builtin_amdgcn_mfma_f32_16x16x32_f16(w3f[2][1], C1[u], a2, 0, 0, 0);
            a3 = __builtin_amdgcn_mfma_f32_16x16x32_f16(w3f[3][1], C1[u], a3, 0, 0, 0);
            E0[u] = act8p(a0, a2);
            E1[u] = act8p(a1, a3);
        }

        // ---- layer 4 + store ----
        floatx4 a4[2];
        #pragma unroll
        for (int u = 0; u < 2; ++u) {
            a4[u] = __builtin_amdgcn_mfma_f32_16x16x32_f16(w4f[0], E0[u], a4init, 0, 0, 0);
            a4[u] = __builtin_amdgcn_mfma_f32_16x16x32_f16(w4f[1], E1[u], a4[u], 0, 0, 0);
        }
        if (q == 0) {
            out[(pair << 5) + m]      = act_poly(a4[0][0]);
            out[(pair << 5) + 16 + m] = act_poly(a4[1][0]);
        }

        xv[0] = xn[0]; xv[1] = xn[1];
        pair = np;
    }
}

extern "C" void kernel_launch(void* const* d_in, const int* in_sizes, int n_in,
                              void* d_out, int out_size, void* d_ws, size_t ws_size,
                              hipStream_t stream) {
    const float* x  = (const float*)d_in[0];
    const float* W1 = (const float*)d_in[1];
    const float* b1 = (const float*)d_in[2];
    const float* W2 = (const float*)d_in[3];
    const float* b2 = (const float*)d_in[4];
    const float* W3 = (const float*)d_in[5];
    const float* b3 = (const float*)d_in[6];
    const float* W4 = (const float*)d_in[7];
    const float* b4 = (const float*)d_in[8];
    float* out = (float*)d_out;
    const int N = out_size;          // 2097152, divisible by 32

    // 4096 blocks x 4 waves = 16384 waves; 65536 tile-pairs -> 4 iterations/wave.
    mlp_fused<<<dim3(4096), dim3(256), 0, stream>>>(x, W1, b1, W2, b2, W3, b3, W4, b4, out, N);
}

// Round 9
// 171.886 us; speedup vs baseline: 1.4251x; 1.4251x over previous
//
#include <hip/hip_runtime.h>

typedef _Float16 half8  __attribute__((ext_vector_type(8)));
typedef _Float16 half4v __attribute__((ext_vector_type(4)));
typedef _Float16 half2v __attribute__((ext_vector_type(2)));
typedef float    floatx4 __attribute__((ext_vector_type(4)));
typedef float    float2v __attribute__((ext_vector_type(2)));

static constexpr float INV2PI = 0.15915494309189535f;  // fold rad->rev into weights
static constexpr float RLOG   = 3.82843f;

// act(a), a in revolutions: x0 = 0.5+0.5cos -> two logistic iters.
// p = x0(1-x0) = 0.25 - 0.25 c^2;  out = R^2 * p * (1 - R*p).
// (cos version: R8 proved the poly replacement costs MORE VALU issue.)
__device__ __forceinline__ float act_rev(float a) {
    float c = __builtin_amdgcn_cosf(a);
    float qq = c * c;
    float p = __builtin_fmaf(qq, -0.25f, 0.25f);
    float w = __builtin_fmaf(p, -RLOG, 1.0f);
    return (RLOG * RLOG * p) * w;
}

// Two C-frags (tiles t, t+2) -> next-layer B-frag directly (no cat shuffles).
__device__ __forceinline__ half8 act8(floatx4 a, floatx4 b) {
    float2v c0 = { __builtin_amdgcn_cosf(a[0]), __builtin_amdgcn_cosf(a[1]) };
    float2v c1 = { __builtin_amdgcn_cosf(a[2]), __builtin_amdgcn_cosf(a[3]) };
    float2v c2 = { __builtin_amdgcn_cosf(b[0]), __builtin_amdgcn_cosf(b[1]) };
    float2v c3 = { __builtin_amdgcn_cosf(b[2]), __builtin_amdgcn_cosf(b[3]) };
    float2v q0 = c0*c0, q1 = c1*c1, q2 = c2*c2, q3 = c3*c3;
    float2v p0 = __builtin_elementwise_fma(q0, (float2v)(-0.25f), (float2v)(0.25f));
    float2v p1 = __builtin_elementwise_fma(q1, (float2v)(-0.25f), (float2v)(0.25f));
    float2v p2 = __builtin_elementwise_fma(q2, (float2v)(-0.25f), (float2v)(0.25f));
    float2v p3 = __builtin_elementwise_fma(q3, (float2v)(-0.25f), (float2v)(0.25f));
    float2v w0 = __builtin_elementwise_fma(p0, (float2v)(-RLOG), (float2v)(1.0f));
    float2v w1 = __builtin_elementwise_fma(p1, (float2v)(-RLOG), (float2v)(1.0f));
    float2v w2 = __builtin_elementwise_fma(p2, (float2v)(-RLOG), (float2v)(1.0f));
    float2v w3 = __builtin_elementwise_fma(p3, (float2v)(-RLOG), (float2v)(1.0f));
    const float R2 = RLOG * RLOG;
    float2v h0 = (p0*R2)*w0, h1 = (p1*R2)*w1, h2 = (p2*R2)*w2, h3 = (p3*R2)*w3;
    half2v e0 = __builtin_bit_cast(half2v, __builtin_amdgcn_cvt_pkrtz(h0.x, h0.y));
    half2v e1 = __builtin_bit_cast(half2v, __builtin_amdgcn_cvt_pkrtz(h1.x, h1.y));
    half2v e2 = __builtin_bit_cast(half2v, __builtin_amdgcn_cvt_pkrtz(h2.x, h2.y));
    half2v e3 = __builtin_bit_cast(half2v, __builtin_amdgcn_cvt_pkrtz(h3.x, h3.y));
    half4v lo = __builtin_shufflevector(e0, e1, 0, 1, 2, 3);
    half4v hi = __builtin_shufflevector(e2, e3, 0, 1, 2, 3);
    return __builtin_shufflevector(lo, hi, 0, 1, 2, 3, 4, 5, 6, 7);
}

// Per-block LDS weight cache: w2/w3 A-frags + f32 bias C-frags, one copy
// shared by the block's 4 waves. Frees ~128 loop-invariant regs/wave so the
// kernel fits launch_bounds(256,3) -> 3 waves/SIMD (R5-R8 were residency-
// capped at 2 with ~50% VALUBusy).
struct SMem {
    half8   w2[8][64];   // [(t*2+c)][lane]
    half8   w3[8][64];
    floatx4 b2[4][64];   // [t][lane]
    floatx4 b3[4][64];
};

__global__ __launch_bounds__(256, 3) void mlp_fused(
    const float* __restrict__ x,
    const float* __restrict__ W1, const float* __restrict__ b1,
    const float* __restrict__ W2, const float* __restrict__ b2,
    const float* __restrict__ W3, const float* __restrict__ b3,
    const float* __restrict__ W4, const float* __restrict__ b4,
    float* __restrict__ out, int N)
{
    __shared__ SMem sm;
    const int lane = threadIdx.x & 63;
    const int wib  = threadIdx.x >> 6;
    const int m    = lane & 15;   // sample / C col / A row
    const int q    = lane >> 4;   // quad
    const float s  = INV2PI;
    const floatx4 zero4 = {0.0f, 0.0f, 0.0f, 0.0f};

    // ---- in-register persistent frags (small): L1 and L4 ----
    // L1 A-frag (tile t), lanes q==0: [w0h, w0h, w0l, w1h, w1h, w1l, b1h, b1l]
    half8 w1f[4];
    #pragma unroll
    for (int t = 0; t < 4; ++t) {
        half8 v = {};
        if (q == 0) {
            const int n = 16 * t + m;
            float w0 = W1[2*n] * s, w1 = W1[2*n+1] * s, bb = b1[n] * s;
            _Float16 w0h = (_Float16)w0; float w0l = w0 - (float)w0h;
            _Float16 w1h = (_Float16)w1; float w1l = w1 - (float)w1h;
            _Float16 bh  = (_Float16)bb; float bl  = bb - (float)bh;
            v[0] = w0h; v[1] = w0h; v[2] = (_Float16)w0l;
            v[3] = w1h; v[4] = w1h; v[5] = (_Float16)w1l;
            v[6] = bh;  v[7] = (_Float16)bl;
        }
        w1f[t] = v;
    }
    // L4 A-frag: only out-row m==0 real; sigma column permutation
    //   sigma: k-slot (c,q,j) -> neuron (j<4 ? 16c+4q+j : 16(c+2)+4q+j-4)
    half8 w4f[2] = {half8{}, half8{}};
    if (m == 0) {
        #pragma unroll
        for (int c = 0; c < 2; ++c)
            #pragma unroll
            for (int j = 0; j < 8; ++j) {
                int nu = (j < 4) ? (16 * c + 4 * q + j) : (16 * (c + 2) + 4 * q + j - 4);
                w4f[c][j] = (_Float16)(W4[nu] * s);
            }
    }
    floatx4 a4init = zero4;
    if (q == 0) a4init[0] = b4[0] * s;       // C row 0 = (q=0, r=0)

    // ---- wave-split LDS prep (sigma-permuted columns), one barrier ----
    if (wib == 0) {
        #pragma unroll
        for (int t = 0; t < 4; ++t) {
            const float* r2 = W2 + (16 * t + m) * 64;
            #pragma unroll
            for (int c = 0; c < 2; ++c) {
                floatx4 lo2 = *(const floatx4*)(r2 + 16 * c + 4 * q);
                floatx4 hi2 = *(const floatx4*)(r2 + 16 * (c + 2) + 4 * q);
                half8 v2;
                #pragma unroll
                for (int j = 0; j < 4; ++j) {
                    v2[j]     = (_Float16)(lo2[j] * s);
                    v2[4 + j] = (_Float16)(hi2[j] * s);
                }
                sm.w2[t * 2 + c][lane] = v2;
            }
        }
    } else if (wib == 1) {
        #pragma unroll
        for (int t = 0; t < 4; ++t) {
            const float* r3 = W3 + (16 * t + m) * 64;
            #pragma unroll
            for (int c = 0; c < 2; ++c) {
                floatx4 lo3 = *(const floatx4*)(r3 + 16 * c + 4 * q);
                floatx4 hi3 = *(const floatx4*)(r3 + 16 * (c + 2) + 4 * q);
                half8 v3;
                #pragma unroll
                for (int j = 0; j < 4; ++j) {
                    v3[j]     = (_Float16)(lo3[j] * s);
                    v3[4 + j] = (_Float16)(hi3[j] * s);
                }
                sm.w3[t * 2 + c][lane] = v3;
            }
        }
    } else if (wib == 2) {
        #pragma unroll
        for (int t = 0; t < 4; ++t) {
            sm.b2[t][lane] = *(const floatx4*)(b2 + 16 * t + 4 * q) * s;
            sm.b3[t][lane] = *(const floatx4*)(b3 + 16 * t + 4 * q) * s;
        }
    }
    __syncthreads();

    const int ntiles = N >> 4;
    const int nwaves = (gridDim.x * blockDim.x) >> 6;
    const int gwave  = (int)(blockIdx.x * blockDim.x + threadIdx.x) >> 6;
    const float2* __restrict__ x2 = (const float2*)x;

    int tile = gwave;
    float2 xv = x2[(tile << 4) + m];          // 1-ahead x prefetch
    while (tile < ntiles) {
        const int nt = tile + nwaves;
        float2 xnext;
        if (nt < ntiles) xnext = x2[(nt << 4) + m];

        // L1 B-frag (lanes q==0): [xh, xl, xh, yh, yl, yh, 1, 1]
        half8 xa = {};
        if (q == 0) {
            _Float16 xh = (_Float16)xv.x; float xl = xv.x - (float)xh;
            _Float16 yh = (_Float16)xv.y; float yl = xv.y - (float)yh;
            xa[0] = xh; xa[1] = (_Float16)xl; xa[2] = xh;
            xa[3] = yh; xa[4] = (_Float16)yl; xa[5] = yh;
            xa[6] = (_Float16)1.0f; xa[7] = (_Float16)1.0f;
        }

        // ---- layer 1 (in-register frags) ----
        floatx4 a0 = __builtin_amdgcn_mfma_f32_16x16x32_f16(w1f[0], xa, zero4, 0, 0, 0);
        floatx4 a1 = __builtin_amdgcn_mfma_f32_16x16x32_f16(w1f[1], xa, zero4, 0, 0, 0);
        floatx4 a2 = __builtin_amdgcn_mfma_f32_16x16x32_f16(w1f[2], xa, zero4, 0, 0, 0);
        floatx4 a3 = __builtin_amdgcn_mfma_f32_16x16x32_f16(w1f[3], xa, zero4, 0, 0, 0);
        half8 B0 = act8(a0, a2);
        half8 B1 = act8(a1, a3);

        // Opaque zero per layer: defeats LICM (else the LDS reads hoist back
        // into ~128 live regs and spill) AND staggers reads so peak staging
        // is one layer's worth.
        int z2 = 0; asm volatile("" : "+v"(z2));
        const int l2i = lane + z2;
        a0 = __builtin_amdgcn_mfma_f32_16x16x32_f16(sm.w2[0][l2i], B0, sm.b2[0][l2i], 0, 0, 0);
        a1 = __builtin_amdgcn_mfma_f32_16x16x32_f16(sm.w2[2][l2i], B0, sm.b2[1][l2i], 0, 0, 0);
        a2 = __builtin_amdgcn_mfma_f32_16x16x32_f16(sm.w2[4][l2i], B0, sm.b2[2][l2i], 0, 0, 0);
        a3 = __builtin_amdgcn_mfma_f32_16x16x32_f16(sm.w2[6][l2i], B0, sm.b2[3][l2i], 0, 0, 0);
        a0 = __builtin_amdgcn_mfma_f32_16x16x32_f16(sm.w2[1][l2i], B1, a0, 0, 0, 0);
        a1 = __builtin_amdgcn_mfma_f32_16x16x32_f16(sm.w2[3][l2i], B1, a1, 0, 0, 0);
        a2 = __builtin_amdgcn_mfma_f32_16x16x32_f16(sm.w2[5][l2i], B1, a2, 0, 0, 0);
        a3 = __builtin_amdgcn_mfma_f32_16x16x32_f16(sm.w2[7][l2i], B1, a3, 0, 0, 0);
        half8 C0 = act8(a0, a2);
        half8 C1 = act8(a1, a3);

        int z3 = 0; asm volatile("" : "+v"(z3));
        const int l3i = lane + z3;
        a0 = __builtin_amdgcn_mfma_f32_16x16x32_f16(sm.w3[0][l3i], C0, sm.b3[0][l3i], 0, 0, 0);
        a1 = __builtin_amdgcn_mfma_f32_16x16x32_f16(sm.w3[2][l3i], C0, sm.b3[1][l3i], 0, 0, 0);
        a2 = __builtin_amdgcn_mfma_f32_16x16x32_f16(sm.w3[4][l3i], C0, sm.b3[2][l3i], 0, 0, 0);
        a3 = __builtin_amdgcn_mfma_f32_16x16x32_f16(sm.w3[6][l3i], C0, sm.b3[3][l3i], 0, 0, 0);
        a0 = __builtin_amdgcn_mfma_f32_16x16x32_f16(sm.w3[1][l3i], C1, a0, 0, 0, 0);
        a1 = __builtin_amdgcn_mfma_f32_16x16x32_f16(sm.w3[3][l3i], C1, a1, 0, 0, 0);
        a2 = __builtin_amdgcn_mfma_f32_16x16x32_f16(sm.w3[5][l3i], C1, a2, 0, 0, 0);
        a3 = __builtin_amdgcn_mfma_f32_16x16x32_f16(sm.w3[7][l3i], C1, a3, 0, 0, 0);
        half8 D0 = act8(a0, a2);
        half8 D1 = act8(a1, a3);

        // ---- layer 4 + store ----
        floatx4 a4 = __builtin_amdgcn_mfma_f32_16x16x32_f16(w4f[0], D0, a4init, 0, 0, 0);
        a4 = __builtin_amdgcn_mfma_f32_16x16x32_f16(w4f[1], D1, a4, 0, 0, 0);
        if (q == 0)
            out[(tile << 4) + m] = act_rev(a4[0]);

        xv = xnext;
        tile = nt;
    }
}

extern "C" void kernel_launch(void* const* d_in, const int* in_sizes, int n_in,
                              void* d_out, int out_size, void* d_ws, size_t ws_size,
                              hipStream_t stream) {
    const float* x  = (const float*)d_in[0];
    const float* W1 = (const float*)d_in[1];
    const float* b1 = (const float*)d_in[2];
    const float* W2 = (const float*)d_in[3];
    const float* b2 = (const float*)d_in[4];
    const float* W3 = (const float*)d_in[5];
    const float* b3 = (const float*)d_in[6];
    const float* W4 = (const float*)d_in[7];
    const float* b4 = (const float*)d_in[8];
    float* out = (float*)d_out;
    const int N = out_size;          // 2097152, divisible by 16

    // 4096 blocks x 4 waves = 16384 waves; 131072 tiles -> exactly 8 tiles/wave.
    mlp_fused<<<dim3(4096), dim3(256), 0, stream>>>(x, W1, b1, W2, b2, W3, b3, W4, b4, out, N);
}

// Round 10
// 160.574 us; speedup vs baseline: 1.5255x; 1.0705x over previous
//
#include <hip/hip_runtime.h>

typedef _Float16 half8  __attribute__((ext_vector_type(8)));
typedef _Float16 half4v __attribute__((ext_vector_type(4)));
typedef _Float16 half2v __attribute__((ext_vector_type(2)));
typedef float    floatx4 __attribute__((ext_vector_type(4)));
typedef float    float2v __attribute__((ext_vector_type(2)));

static constexpr float INV2PI = 0.15915494309189535f;  // fold rad->rev into weights
static constexpr float RLOG   = 3.82843f;

// Fused activation: x0 = 0.5+0.5cos(2*pi*a); two logistic iters.
// With u = cos^2:  p = (1-u)/4,  h = R^2 p (1 - R p) = A + u*(B + D*u).
static constexpr double RD = (double)RLOG;
static constexpr float ACT_A = (float)(RD*RD/4.0 - RD*RD*RD/16.0);
static constexpr float ACT_B = (float)(-RD*RD/4.0 + RD*RD*RD/8.0);
static constexpr float ACT_D = (float)(-RD*RD*RD/16.0);

__device__ __forceinline__ float act_rev(float a) {
    float c = __builtin_amdgcn_cosf(a);
    float u = c * c;
    float t = __builtin_fmaf(ACT_D, u, ACT_B);
    return __builtin_fmaf(u, t, ACT_A);
}

// Two C-frags (tiles t, t+2) -> next-layer B-frag directly (no cat shuffles).
// Per 2 activations: 2x v_cos + 3 packed-f32 ops (R9's version used 5).
__device__ __forceinline__ half8 act8(floatx4 a, floatx4 b) {
    float2v c0 = { __builtin_amdgcn_cosf(a[0]), __builtin_amdgcn_cosf(a[1]) };
    float2v c1 = { __builtin_amdgcn_cosf(a[2]), __builtin_amdgcn_cosf(a[3]) };
    float2v c2 = { __builtin_amdgcn_cosf(b[0]), __builtin_amdgcn_cosf(b[1]) };
    float2v c3 = { __builtin_amdgcn_cosf(b[2]), __builtin_amdgcn_cosf(b[3]) };
    float2v u0 = c0*c0, u1 = c1*c1, u2 = c2*c2, u3 = c3*c3;
    float2v t0 = __builtin_elementwise_fma(u0, (float2v)(ACT_D), (float2v)(ACT_B));
    float2v t1 = __builtin_elementwise_fma(u1, (float2v)(ACT_D), (float2v)(ACT_B));
    float2v t2 = __builtin_elementwise_fma(u2, (float2v)(ACT_D), (float2v)(ACT_B));
    float2v t3 = __builtin_elementwise_fma(u3, (float2v)(ACT_D), (float2v)(ACT_B));
    float2v h0 = __builtin_elementwise_fma(u0, t0, (float2v)(ACT_A));
    float2v h1 = __builtin_elementwise_fma(u1, t1, (float2v)(ACT_A));
    float2v h2 = __builtin_elementwise_fma(u2, t2, (float2v)(ACT_A));
    float2v h3 = __builtin_elementwise_fma(u3, t3, (float2v)(ACT_A));
    half2v e0 = __builtin_bit_cast(half2v, __builtin_amdgcn_cvt_pkrtz(h0.x, h0.y));
    half2v e1 = __builtin_bit_cast(half2v, __builtin_amdgcn_cvt_pkrtz(h1.x, h1.y));
    half2v e2 = __builtin_bit_cast(half2v, __builtin_amdgcn_cvt_pkrtz(h2.x, h2.y));
    half2v e3 = __builtin_bit_cast(half2v, __builtin_amdgcn_cvt_pkrtz(h3.x, h3.y));
    half4v lo = __builtin_shufflevector(e0, e1, 0, 1, 2, 3);
    half4v hi = __builtin_shufflevector(e2, e3, 0, 1, 2, 3);
    return __builtin_shufflevector(lo, hi, 0, 1, 2, 3, 4, 5, 6, 7);
}

// Per-block LDS weight cache: w2/w3 A-frags + f32 bias C-frags, one copy
// shared by the block's 4 waves (R9: freed ~100 regs/wave, VGPR 96->52).
// launch_bounds(256,6): VGPR cap 84 (use ~52), LDS 24.6KB -> 6 blocks/CU,
// occupancy ceiling 75% (R9's (256,3) was the binding cap at 39%).
struct SMem {
    half8   w2[8][64];   // [(t*2+c)][lane]
    half8   w3[8][64];
    floatx4 b2[4][64];   // [t][lane]
    floatx4 b3[4][64];
};

__global__ __launch_bounds__(256, 6) void mlp_fused(
    const float* __restrict__ x,
    const float* __restrict__ W1, const float* __restrict__ b1,
    const float* __restrict__ W2, const float* __restrict__ b2,
    const float* __restrict__ W3, const float* __restrict__ b3,
    const float* __restrict__ W4, const float* __restrict__ b4,
    float* __restrict__ out, int N)
{
    __shared__ SMem sm;
    const int lane = threadIdx.x & 63;
    const int wib  = threadIdx.x >> 6;
    const int m    = lane & 15;   // sample / C col / A row
    const int q    = lane >> 4;   // quad
    const float s  = INV2PI;
    const floatx4 zero4 = {0.0f, 0.0f, 0.0f, 0.0f};

    // ---- in-register persistent frags (small): L1 and L4 ----
    // L1 A-frag (tile t), lanes q==0: [w0h, w0h, w0l, w1h, w1h, w1l, b1h, b1l]
    half8 w1f[4];
    #pragma unroll
    for (int t = 0; t < 4; ++t) {
        half8 v = {};
        if (q == 0) {
            const int n = 16 * t + m;
            float w0 = W1[2*n] * s, w1 = W1[2*n+1] * s, bb = b1[n] * s;
            _Float16 w0h = (_Float16)w0; float w0l = w0 - (float)w0h;
            _Float16 w1h = (_Float16)w1; float w1l = w1 - (float)w1h;
            _Float16 bh  = (_Float16)bb; float bl  = bb - (float)bh;
            v[0] = w0h; v[1] = w0h; v[2] = (_Float16)w0l;
            v[3] = w1h; v[4] = w1h; v[5] = (_Float16)w1l;
            v[6] = bh;  v[7] = (_Float16)bl;
        }
        w1f[t] = v;
    }
    // L4 A-frag: only out-row m==0 real; sigma column permutation
    //   sigma: k-slot (c,q,j) -> neuron (j<4 ? 16c+4q+j : 16(c+2)+4q+j-4)
    half8 w4f[2] = {half8{}, half8{}};
    if (m == 0) {
        #pragma unroll
        for (int c = 0; c < 2; ++c)
            #pragma unroll
            for (int j = 0; j < 8; ++j) {
                int nu = (j < 4) ? (16 * c + 4 * q + j) : (16 * (c + 2) + 4 * q + j - 4);
                w4f[c][j] = (_Float16)(W4[nu] * s);
            }
    }
    floatx4 a4init = zero4;
    if (q == 0) a4init[0] = b4[0] * s;       // C row 0 = (q=0, r=0)

    // ---- wave-split LDS prep (sigma-permuted columns), one barrier ----
    if (wib == 0) {
        #pragma unroll
        for (int t = 0; t < 4; ++t) {
            const float* r2 = W2 + (16 * t + m) * 64;
            #pragma unroll
            for (int c = 0; c < 2; ++c) {
                floatx4 lo2 = *(const floatx4*)(r2 + 16 * c + 4 * q);
                floatx4 hi2 = *(const floatx4*)(r2 + 16 * (c + 2) + 4 * q);
                half8 v2;
                #pragma unroll
                for (int j = 0; j < 4; ++j) {
                    v2[j]     = (_Float16)(lo2[j] * s);
                    v2[4 + j] = (_Float16)(hi2[j] * s);
                }
                sm.w2[t * 2 + c][lane] = v2;
            }
        }
    } else if (wib == 1) {
        #pragma unroll
        for (int t = 0; t < 4; ++t) {
            const float* r3 = W3 + (16 * t + m) * 64;
            #pragma unroll
            for (int c = 0; c < 2; ++c) {
                floatx4 lo3 = *(const floatx4*)(r3 + 16 * c + 4 * q);
                floatx4 hi3 = *(const floatx4*)(r3 + 16 * (c + 2) + 4 * q);
                half8 v3;
                #pragma unroll
                for (int j = 0; j < 4; ++j) {
                    v3[j]     = (_Float16)(lo3[j] * s);
                    v3[4 + j] = (_Float16)(hi3[j] * s);
                }
                sm.w3[t * 2 + c][lane] = v3;
            }
        }
    } else if (wib == 2) {
        #pragma unroll
        for (int t = 0; t < 4; ++t) {
            sm.b2[t][lane] = *(const floatx4*)(b2 + 16 * t + 4 * q) * s;
            sm.b3[t][lane] = *(const floatx4*)(b3 + 16 * t + 4 * q) * s;
        }
    }
    __syncthreads();

    const int ntiles = N >> 4;
    const int nwaves = (gridDim.x * blockDim.x) >> 6;
    const int gwave  = (int)(blockIdx.x * blockDim.x + threadIdx.x) >> 6;
    const float2* __restrict__ x2 = (const float2*)x;

    int tile = gwave;
    float2 xv = x2[(tile << 4) + m];          // 1-ahead x prefetch
    while (tile < ntiles) {
        const int nt = tile + nwaves;
        float2 xnext;
        if (nt < ntiles) xnext = x2[(nt << 4) + m];

        // L1 B-frag (lanes q==0): [xh, xl, xh, yh, yl, yh, 1, 1]
        half8 xa = {};
        if (q == 0) {
            _Float16 xh = (_Float16)xv.x; float xl = xv.x - (float)xh;
            _Float16 yh = (_Float16)xv.y; float yl = xv.y - (float)yh;
            xa[0] = xh; xa[1] = (_Float16)xl; xa[2] = xh;
            xa[3] = yh; xa[4] = (_Float16)yl; xa[5] = yh;
            xa[6] = (_Float16)1.0f; xa[7] = (_Float16)1.0f;
        }

        // ---- layer 1 (in-register frags) ----
        floatx4 a0 = __builtin_amdgcn_mfma_f32_16x16x32_f16(w1f[0], xa, zero4, 0, 0, 0);
        floatx4 a1 = __builtin_amdgcn_mfma_f32_16x16x32_f16(w1f[1], xa, zero4, 0, 0, 0);
        floatx4 a2 = __builtin_amdgcn_mfma_f32_16x16x32_f16(w1f[2], xa, zero4, 0, 0, 0);
        floatx4 a3 = __builtin_amdgcn_mfma_f32_16x16x32_f16(w1f[3], xa, zero4, 0, 0, 0);
        half8 B0 = act8(a0, a2);
        half8 B1 = act8(a1, a3);

        // Opaque zero per layer: defeats LICM (else the LDS reads hoist back
        // into ~128 live regs and spill) AND staggers reads so peak staging
        // is one layer's worth.
        int z2 = 0; asm volatile("" : "+v"(z2));
        const int l2i = lane + z2;
        a0 = __builtin_amdgcn_mfma_f32_16x16x32_f16(sm.w2[0][l2i], B0, sm.b2[0][l2i], 0, 0, 0);
        a1 = __builtin_amdgcn_mfma_f32_16x16x32_f16(sm.w2[2][l2i], B0, sm.b2[1][l2i], 0, 0, 0);
        a2 = __builtin_amdgcn_mfma_f32_16x16x32_f16(sm.w2[4][l2i], B0, sm.b2[2][l2i], 0, 0, 0);
        a3 = __builtin_amdgcn_mfma_f32_16x16x32_f16(sm.w2[6][l2i], B0, sm.b2[3][l2i], 0, 0, 0);
        a0 = __builtin_amdgcn_mfma_f32_16x16x32_f16(sm.w2[1][l2i], B1, a0, 0, 0, 0);
        a1 = __builtin_amdgcn_mfma_f32_16x16x32_f16(sm.w2[3][l2i], B1, a1, 0, 0, 0);
        a2 = __builtin_amdgcn_mfma_f32_16x16x32_f16(sm.w2[5][l2i], B1, a2, 0, 0, 0);
        a3 = __builtin_amdgcn_mfma_f32_16x16x32_f16(sm.w2[7][l2i], B1, a3, 0, 0, 0);
        half8 C0 = act8(a0, a2);
        half8 C1 = act8(a1, a3);

        int z3 = 0; asm volatile("" : "+v"(z3));
        const int l3i = lane + z3;
        a0 = __builtin_amdgcn_mfma_f32_16x16x32_f16(sm.w3[0][l3i], C0, sm.b3[0][l3i], 0, 0, 0);
        a1 = __builtin_amdgcn_mfma_f32_16x16x32_f16(sm.w3[2][l3i], C0, sm.b3[1][l3i], 0, 0, 0);
        a2 = __builtin_amdgcn_mfma_f32_16x16x32_f16(sm.w3[4][l3i], C0, sm.b3[2][l3i], 0, 0, 0);
        a3 = __builtin_amdgcn_mfma_f32_16x16x32_f16(sm.w3[6][l3i], C0, sm.b3[3][l3i], 0, 0, 0);
        a0 = __builtin_amdgcn_mfma_f32_16x16x32_f16(sm.w3[1][l3i], C1, a0, 0, 0, 0);
        a1 = __builtin_amdgcn_mfma_f32_16x16x32_f16(sm.w3[3][l3i], C1, a1, 0, 0, 0);
        a2 = __builtin_amdgcn_mfma_f32_16x16x32_f16(sm.w3[5][l3i], C1, a2, 0, 0, 0);
        a3 = __builtin_amdgcn_mfma_f32_16x16x32_f16(sm.w3[7][l3i], C1, a3, 0, 0, 0);
        half8 D0 = act8(a0, a2);
        half8 D1 = act8(a1, a3);

        // ---- layer 4 + store ----
        floatx4 a4 = __builtin_amdgcn_mfma_f32_16x16x32_f16(w4f[0], D0, a4init, 0, 0, 0);
        a4 = __builtin_amdgcn_mfma_f32_16x16x32_f16(w4f[1], D1, a4, 0, 0, 0);
        if (q == 0)
            out[(tile << 4) + m] = act_rev(a4[0]);

        xv = xnext;
        tile = nt;
    }
}

extern "C" void kernel_launch(void* const* d_in, const int* in_sizes, int n_in,
                              void* d_out, int out_size, void* d_ws, size_t ws_size,
                              hipStream_t stream) {
    const float* x  = (const float*)d_in[0];
    const float* W1 = (const float*)d_in[1];
    const float* b1 = (const float*)d_in[2];
    const float* W2 = (const float*)d_in[3];
    const float* b2 = (const float*)d_in[4];
    const float* W3 = (const float*)d_in[5];
    const float* b3 = (const float*)d_in[6];
    const float* W4 = (const float*)d_in[7];
    const float* b4 = (const float*)d_in[8];
    float* out = (float*)d_out;
    const int N = out_size;          // 2097152, divisible by 16

    // 4096 blocks x 4 waves = 16384 waves; 131072 tiles -> exactly 8 tiles/wave.
    mlp_fused<<<dim3(4096), dim3(256), 0, stream>>>(x, W1, b1, W2, b2, W3, b3, W4, b4, out, N);
}

// Round 11
// 158.241 us; speedup vs baseline: 1.5479x; 1.0147x over previous
//
#include <hip/hip_runtime.h>

typedef _Float16 half8  __attribute__((ext_vector_type(8)));
typedef _Float16 half4v __attribute__((ext_vector_type(4)));
typedef _Float16 half2v __attribute__((ext_vector_type(2)));
typedef float    floatx4 __attribute__((ext_vector_type(4)));
typedef float    float2v __attribute__((ext_vector_type(2)));

static constexpr float INV2PI = 0.15915494309189535f;  // fold rad->rev into weights
static constexpr float RLOG   = 3.82843f;

// Fused activation: x0 = 0.5+0.5cos(2*pi*a); two logistic iters.
// With u = cos^2:  p = (1-u)/4,  h = R^2 p (1 - R p) = A + u*(B + D*u).
static constexpr double RD = (double)RLOG;
static constexpr float ACT_A = (float)(RD*RD/4.0 - RD*RD*RD/16.0);
static constexpr float ACT_B = (float)(-RD*RD/4.0 + RD*RD*RD/8.0);
static constexpr float ACT_D = (float)(-RD*RD*RD/16.0);

__device__ __forceinline__ float act_rev(float a) {
    float c = __builtin_amdgcn_cosf(a);
    float u = c * c;
    float t = __builtin_fmaf(ACT_D, u, ACT_B);
    return __builtin_fmaf(u, t, ACT_A);
}

// Two C-frags (tiles t, t+2) -> next-layer B-frag directly (no cat shuffles).
// Per 2 activations: 2x v_cos + 3 packed-f32 ops.
__device__ __forceinline__ half8 act8(floatx4 a, floatx4 b) {
    float2v c0 = { __builtin_amdgcn_cosf(a[0]), __builtin_amdgcn_cosf(a[1]) };
    float2v c1 = { __builtin_amdgcn_cosf(a[2]), __builtin_amdgcn_cosf(a[3]) };
    float2v c2 = { __builtin_amdgcn_cosf(b[0]), __builtin_amdgcn_cosf(b[1]) };
    float2v c3 = { __builtin_amdgcn_cosf(b[2]), __builtin_amdgcn_cosf(b[3]) };
    float2v u0 = c0*c0, u1 = c1*c1, u2 = c2*c2, u3 = c3*c3;
    float2v t0 = __builtin_elementwise_fma(u0, (float2v)(ACT_D), (float2v)(ACT_B));
    float2v t1 = __builtin_elementwise_fma(u1, (float2v)(ACT_D), (float2v)(ACT_B));
    float2v t2 = __builtin_elementwise_fma(u2, (float2v)(ACT_D), (float2v)(ACT_B));
    float2v t3 = __builtin_elementwise_fma(u3, (float2v)(ACT_D), (float2v)(ACT_B));
    float2v h0 = __builtin_elementwise_fma(u0, t0, (float2v)(ACT_A));
    float2v h1 = __builtin_elementwise_fma(u1, t1, (float2v)(ACT_A));
    float2v h2 = __builtin_elementwise_fma(u2, t2, (float2v)(ACT_A));
    float2v h3 = __builtin_elementwise_fma(u3, t3, (float2v)(ACT_A));
    half2v e0 = __builtin_bit_cast(half2v, __builtin_amdgcn_cvt_pkrtz(h0.x, h0.y));
    half2v e1 = __builtin_bit_cast(half2v, __builtin_amdgcn_cvt_pkrtz(h1.x, h1.y));
    half2v e2 = __builtin_bit_cast(half2v, __builtin_amdgcn_cvt_pkrtz(h2.x, h2.y));
    half2v e3 = __builtin_bit_cast(half2v, __builtin_amdgcn_cvt_pkrtz(h3.x, h3.y));
    half4v lo = __builtin_shufflevector(e0, e1, 0, 1, 2, 3);
    half4v hi = __builtin_shufflevector(e2, e3, 0, 1, 2, 3);
    return __builtin_shufflevector(lo, hi, 0, 1, 2, 3, 4, 5, 6, 7);
}

// Per-block LDS weight cache: w2/w3 A-frags + f32 bias C-frags.
// R10 stalled at 53% occupancy: 24.6KB per 256-thread block caps resident
// blocks at ~5/CU. Same SMem shared by a 512-thread block (8 waves) -> 4
// blocks/CU = 32 waves/CU (100% ceiling) at 98KB LDS.
// launch_bounds(512,8): VGPR cap 64 (R10 used 40 — safe margin).
struct SMem {
    half8   w2[8][64];   // [(t*2+c)][lane]
    half8   w3[8][64];
    floatx4 b2[4][64];   // [t][lane]
    floatx4 b3[4][64];
};

__global__ __launch_bounds__(512, 8) void mlp_fused(
    const float* __restrict__ x,
    const float* __restrict__ W1, const float* __restrict__ b1,
    const float* __restrict__ W2, const float* __restrict__ b2,
    const float* __restrict__ W3, const float* __restrict__ b3,
    const float* __restrict__ W4, const float* __restrict__ b4,
    float* __restrict__ out, int N)
{
    __shared__ SMem sm;
    const int lane = threadIdx.x & 63;
    const int wib  = threadIdx.x >> 6;   // 0..7
    const int m    = lane & 15;   // sample / C col / A row
    const int q    = lane >> 4;   // quad
    const float s  = INV2PI;
    const floatx4 zero4 = {0.0f, 0.0f, 0.0f, 0.0f};

    // ---- in-register persistent frags (small): L1 and L4 ----
    // L1 A-frag (tile t), lanes q==0: [w0h, w0h, w0l, w1h, w1h, w1l, b1h, b1l]
    half8 w1f[4];
    #pragma unroll
    for (int t = 0; t < 4; ++t) {
        half8 v = {};
        if (q == 0) {
            const int n = 16 * t + m;
            float w0 = W1[2*n] * s, w1 = W1[2*n+1] * s, bb = b1[n] * s;
            _Float16 w0h = (_Float16)w0; float w0l = w0 - (float)w0h;
            _Float16 w1h = (_Float16)w1; float w1l = w1 - (float)w1h;
            _Float16 bh  = (_Float16)bb; float bl  = bb - (float)bh;
            v[0] = w0h; v[1] = w0h; v[2] = (_Float16)w0l;
            v[3] = w1h; v[4] = w1h; v[5] = (_Float16)w1l;
            v[6] = bh;  v[7] = (_Float16)bl;
        }
        w1f[t] = v;
    }
    // L4 A-frag: only out-row m==0 real; sigma column permutation
    //   sigma: k-slot (c,q,j) -> neuron (j<4 ? 16c+4q+j : 16(c+2)+4q+j-4)
    half8 w4f[2] = {half8{}, half8{}};
    if (m == 0) {
        #pragma unroll
        for (int c = 0; c < 2; ++c)
            #pragma unroll
            for (int j = 0; j < 8; ++j) {
                int nu = (j < 4) ? (16 * c + 4 * q + j) : (16 * (c + 2) + 4 * q + j - 4);
                w4f[c][j] = (_Float16)(W4[nu] * s);
            }
    }
    floatx4 a4init = zero4;
    if (q == 0) a4init[0] = b4[0] * s;       // C row 0 = (q=0, r=0)

    // ---- wave-split LDS prep (sigma-permuted columns), one barrier ----
    if (wib == 0) {
        #pragma unroll
        for (int t = 0; t < 4; ++t) {
            const float* r2 = W2 + (16 * t + m) * 64;
            #pragma unroll
            for (int c = 0; c < 2; ++c) {
                floatx4 lo2 = *(const floatx4*)(r2 + 16 * c + 4 * q);
                floatx4 hi2 = *(const floatx4*)(r2 + 16 * (c + 2) + 4 * q);
                half8 v2;
                #pragma unroll
                for (int j = 0; j < 4; ++j) {
                    v2[j]     = (_Float16)(lo2[j] * s);
                    v2[4 + j] = (_Float16)(hi2[j] * s);
                }
                sm.w2[t * 2 + c][lane] = v2;
            }
        }
    } else if (wib == 1) {
        #pragma unroll
        for (int t = 0; t < 4; ++t) {
            const float* r3 = W3 + (16 * t + m) * 64;
            #pragma unroll
            for (int c = 0; c < 2; ++c) {
                floatx4 lo3 = *(const floatx4*)(r3 + 16 * c + 4 * q);
                floatx4 hi3 = *(const floatx4*)(r3 + 16 * (c + 2) + 4 * q);
                half8 v3;
                #pragma unroll
                for (int j = 0; j < 4; ++j) {
                    v3[j]     = (_Float16)(lo3[j] * s);
                    v3[4 + j] = (_Float16)(hi3[j] * s);
                }
                sm.w3[t * 2 + c][lane] = v3;
            }
        }
    } else if (wib == 2) {
        #pragma unroll
        for (int t = 0; t < 4; ++t) {
            sm.b2[t][lane] = *(const floatx4*)(b2 + 16 * t + 4 * q) * s;
            sm.b3[t][lane] = *(const floatx4*)(b3 + 16 * t + 4 * q) * s;
        }
    }
    __syncthreads();

    const int ntiles = N >> 4;
    const int nwaves = (gridDim.x * blockDim.x) >> 6;
    const int gwave  = (int)(blockIdx.x * blockDim.x + threadIdx.x) >> 6;
    const float2* __restrict__ x2 = (const float2*)x;

    int tile = gwave;
    float2 xv = x2[(tile << 4) + m];          // 1-ahead x prefetch
    while (tile < ntiles) {
        const int nt = tile + nwaves;
        float2 xnext;
        if (nt < ntiles) xnext = x2[(nt << 4) + m];

        // L1 B-frag (lanes q==0): [xh, xl, xh, yh, yl, yh, 1, 1]
        half8 xa = {};
        if (q == 0) {
            _Float16 xh = (_Float16)xv.x; float xl = xv.x - (float)xh;
            _Float16 yh = (_Float16)xv.y; float yl = xv.y - (float)yh;
            xa[0] = xh; xa[1] = (_Float16)xl; xa[2] = xh;
            xa[3] = yh; xa[4] = (_Float16)yl; xa[5] = yh;
            xa[6] = (_Float16)1.0f; xa[7] = (_Float16)1.0f;
        }

        // ---- layer 1 (in-register frags) ----
        floatx4 a0 = __builtin_amdgcn_mfma_f32_16x16x32_f16(w1f[0], xa, zero4, 0, 0, 0);
        floatx4 a1 = __builtin_amdgcn_mfma_f32_16x16x32_f16(w1f[1], xa, zero4, 0, 0, 0);
        floatx4 a2 = __builtin_amdgcn_mfma_f32_16x16x32_f16(w1f[2], xa, zero4, 0, 0, 0);
        floatx4 a3 = __builtin_amdgcn_mfma_f32_16x16x32_f16(w1f[3], xa, zero4, 0, 0, 0);
        half8 B0 = act8(a0, a2);
        half8 B1 = act8(a1, a3);

        // Opaque zero per layer: defeats LICM (else the LDS reads hoist back
        // into ~128 live regs and spill) AND staggers reads so peak staging
        // is one layer's worth.
        int z2 = 0; asm volatile("" : "+v"(z2));
        const int l2i = lane + z2;
        a0 = __builtin_amdgcn_mfma_f32_16x16x32_f16(sm.w2[0][l2i], B0, sm.b2[0][l2i], 0, 0, 0);
        a1 = __builtin_amdgcn_mfma_f32_16x16x32_f16(sm.w2[2][l2i], B0, sm.b2[1][l2i], 0, 0, 0);
        a2 = __builtin_amdgcn_mfma_f32_16x16x32_f16(sm.w2[4][l2i], B0, sm.b2[2][l2i], 0, 0, 0);
        a3 = __builtin_amdgcn_mfma_f32_16x16x32_f16(sm.w2[6][l2i], B0, sm.b2[3][l2i], 0, 0, 0);
        a0 = __builtin_amdgcn_mfma_f32_16x16x32_f16(sm.w2[1][l2i], B1, a0, 0, 0, 0);
        a1 = __builtin_amdgcn_mfma_f32_16x16x32_f16(sm.w2[3][l2i], B1, a1, 0, 0, 0);
        a2 = __builtin_amdgcn_mfma_f32_16x16x32_f16(sm.w2[5][l2i], B1, a2, 0, 0, 0);
        a3 = __builtin_amdgcn_mfma_f32_16x16x32_f16(sm.w2[7][l2i], B1, a3, 0, 0, 0);
        half8 C0 = act8(a0, a2);
        half8 C1 = act8(a1, a3);

        int z3 = 0; asm volatile("" : "+v"(z3));
        const int l3i = lane + z3;
        a0 = __builtin_amdgcn_mfma_f32_16x16x32_f16(sm.w3[0][l3i], C0, sm.b3[0][l3i], 0, 0, 0);
        a1 = __builtin_amdgcn_mfma_f32_16x16x32_f16(sm.w3[2][l3i], C0, sm.b3[1][l3i], 0, 0, 0);
        a2 = __builtin_amdgcn_mfma_f32_16x16x32_f16(sm.w3[4][l3i], C0, sm.b3[2][l3i], 0, 0, 0);
        a3 = __builtin_amdgcn_mfma_f32_16x16x32_f16(sm.w3[6][l3i], C0, sm.b3[3][l3i], 0, 0, 0);
        a0 = __builtin_amdgcn_mfma_f32_16x16x32_f16(sm.w3[1][l3i], C1, a0, 0, 0, 0);
        a1 = __builtin_amdgcn_mfma_f32_16x16x32_f16(sm.w3[3][l3i], C1, a1, 0, 0, 0);
        a2 = __builtin_amdgcn_mfma_f32_16x16x32_f16(sm.w3[5][l3i], C1, a2, 0, 0, 0);
        a3 = __builtin_amdgcn_mfma_f32_16x16x32_f16(sm.w3[7][l3i], C1, a3, 0, 0, 0);
        half8 D0 = act8(a0, a2);
        half8 D1 = act8(a1, a3);

        // ---- layer 4 + store ----
        floatx4 a4 = __builtin_amdgcn_mfma_f32_16x16x32_f16(w4f[0], D0, a4init, 0, 0, 0);
        a4 = __builtin_amdgcn_mfma_f32_16x16x32_f16(w4f[1], D1, a4, 0, 0, 0);
        if (q == 0)
            out[(tile << 4) + m] = act_rev(a4[0]);

        xv = xnext;
        tile = nt;
    }
}

extern "C" void kernel_launch(void* const* d_in, const int* in_sizes, int n_in,
                              void* d_out, int out_size, void* d_ws, size_t ws_size,
                              hipStream_t stream) {
    const float* x  = (const float*)d_in[0];
    const float* W1 = (const float*)d_in[1];
    const float* b1 = (const float*)d_in[2];
    const float* W2 = (const float*)d_in[3];
    const float* b2 = (const float*)d_in[4];
    const float* W3 = (const float*)d_in[5];
    const float* b3 = (const float*)d_in[6];
    const float* W4 = (const float*)d_in[7];
    const float* b4 = (const float*)d_in[8];
    float* out = (float*)d_out;
    const int N = out_size;          // 2097152, divisible by 16

    // 2048 blocks x 8 waves = 16384 waves; 131072 tiles -> exactly 8 tiles/wave.
    // 512-thread blocks: 4 resident blocks/CU at 24.6KB LDS each = 32 waves/CU.
    mlp_fused<<<dim3(2048), dim3(512), 0, stream>>>(x, W1, b1, W2, b2, W3, b3, W4, b4, out, N);
}